// Round 1
// baseline (478.528 us; speedup 1.0000x reference)
//
#include <hip/hip_runtime.h>
#include <math.h>

// Problem constants
#define BN   32768
#define DIM  256
#define KC   1024
#define BN_EPS 1e-5f

// Output layout (floats) in d_out
#define QX_SIZE   (BN * DIM)          // 8388608
#define LOSS0_OFF (QX_SIZE)           // dictionary_loss
#define LOSS1_OFF (QX_SIZE + 1)       // commitment_loss
#define IDX_OFF   (QX_SIZE + 2)       // 32768 indices (as float)
#define PERP_OFF  (QX_SIZE + 2 + BN)  // perplexity

// Workspace layout (float offsets)
#define WS_SUM    0     // 256
#define WS_SUMSQ  256   // 256
#define WS_COUNT  512   // 1
#define WS_LOSS   513   // 1
#define WS_COUNTS 1024  // 1024
#define WS_MU     2048  // 256
#define WS_SCALE  2304  // 256
#define WS_NV     2560  // 1
#define WS_CNORM  3072  // 1024
// zero region: first 2048 floats (8192 bytes)

// ---------------------------------------------------------------- kernel 1
// Masked per-feature sum / sumsq + valid count. 512 blocks x 256 threads.
__global__ __launch_bounds__(256) void k_stats(const float* __restrict__ x,
                                               const int* __restrict__ mask,
                                               float* __restrict__ ws) {
    int t = threadIdx.x;           // feature d
    int b = blockIdx.x;
    float s = 0.f, ss = 0.f, cnt = 0.f;
    for (int r = b; r < BN; r += gridDim.x) {
        float m = (float)mask[r];
        float v = x[(size_t)r * DIM + t];
        float mv = m * v;
        s += mv;
        ss = fmaf(mv, v, ss);      // m * v * v  (m in {0,1})
        cnt += m;
    }
    atomicAdd(&ws[WS_SUM + t], s);
    atomicAdd(&ws[WS_SUMSQ + t], ss);
    if (t == 0) atomicAdd(&ws[WS_COUNT], cnt);
}

// ---------------------------------------------------------------- kernel 2
// Finalize mu/scale (block 0) and codebook column norms (blocks 1..4).
__global__ __launch_bounds__(256) void k_finalize(const float* __restrict__ e,
                                                  const float* __restrict__ gamma,
                                                  float* __restrict__ ws) {
    int t = threadIdx.x;
    int b = blockIdx.x;
    if (b == 0) {
        float cnt = ws[WS_COUNT];
        float nv = fmaxf(cnt, 1.f);
        float mu = ws[WS_SUM + t] / nv;
        float var = ws[WS_SUMSQ + t] / nv - mu * mu;
        var = fmaxf(var, 0.f);
        ws[WS_MU + t] = mu;
        ws[WS_SCALE + t] = rsqrtf(var + BN_EPS) * gamma[t];
        if (t == 0) ws[WS_NV] = nv;
    } else {
        int k = (b - 1) * 256 + t;
        float acc = 0.f;
        #pragma unroll 8
        for (int d = 0; d < DIM; ++d) {
            float v = e[(size_t)d * KC + k];
            acc = fmaf(v, v, acc);
        }
        ws[WS_CNORM + k] = acc;
    }
}

// ---------------------------------------------------------------- kernel 3
// Main: BN-normalize 32 rows into LDS, f32 GEMM vs all 1024 codes with
// register 8x8 tiles, running argmin, then epilogue (gather + losses).
#define RB  32     // rows per block
#define CB  512    // codes per outer iter (2 iters)
#define DBC 8      // d-chunk per Bs staging
#define APAD 36    // As row stride (32 rows + 4 pad, keeps 16B alignment)

__global__ __launch_bounds__(256, 3) void k_main(const float* __restrict__ x,
                                                 const int* __restrict__ mask,
                                                 const float* __restrict__ e,
                                                 const float* __restrict__ beta,
                                                 float* __restrict__ ws,
                                                 float* __restrict__ out) {
    __shared__ __align__(16) float As[DIM * APAD];   // xb, [d][r] layout, 36864 B
    __shared__ __align__(16) float Bs[DBC * CB];     // e chunk, [dd][k], 16384 B
    __shared__ int   idxs_sh[RB];
    __shared__ float msh[RB];
    __shared__ float wred[4];

    int tid = threadIdx.x;
    int row0 = blockIdx.x * RB;

    // ---- stage A: xb = (x - mu) * scale + beta, transposed into LDS
    float mu = ws[WS_MU + tid];
    float sc = ws[WS_SCALE + tid];
    float bt = beta[tid];
    #pragma unroll 4
    for (int r = 0; r < RB; ++r) {
        float v = x[(size_t)(row0 + r) * DIM + tid];
        As[tid * APAD + r] = fmaf(v - mu, sc, bt);
    }

    int ti = tid >> 6;   // 0..3  -> rows ti*8 .. ti*8+7
    int tj = tid & 63;   // 0..63 -> codes tj*8 .. tj*8+7 (per kb iter)

    float minv[8];
    int   mini[8];
    #pragma unroll
    for (int i = 0; i < 8; ++i) { minv[i] = 3.4e38f; mini[i] = 0; }

    const float4* e4 = (const float4*)e;

    for (int kb = 0; kb < 2; ++kb) {
        int kbase = kb * CB;
        float acc[8][8];
        #pragma unroll
        for (int i = 0; i < 8; ++i)
            #pragma unroll
            for (int j = 0; j < 8; ++j) acc[i][j] = 0.f;

        for (int dc = 0; dc < DIM / DBC; ++dc) {   // 32 chunks
            int d0 = dc * DBC;
            __syncthreads();
            // stage Bs: DBC x CB floats = 1024 float4, 4 per thread
            #pragma unroll
            for (int p = 0; p < 4; ++p) {
                int lin = p * 256 + tid;       // 0..1023
                int dd = lin >> 7;             // 128 float4 per d-row
                int kq = lin & 127;
                *(float4*)&Bs[dd * CB + kq * 4] =
                    e4[(size_t)(d0 + dd) * (KC / 4) + (kbase >> 2) + kq];
            }
            __syncthreads();
            #pragma unroll
            for (int dd = 0; dd < DBC; ++dd) {
                int dg = d0 + dd;
                float4 a0 = *(const float4*)&As[dg * APAD + ti * 8];
                float4 a1 = *(const float4*)&As[dg * APAD + ti * 8 + 4];
                float4 b0 = *(const float4*)&Bs[dd * CB + tj * 8];
                float4 b1 = *(const float4*)&Bs[dd * CB + tj * 8 + 4];
                float a[8] = {a0.x, a0.y, a0.z, a0.w, a1.x, a1.y, a1.z, a1.w};
                float b[8] = {b0.x, b0.y, b0.z, b0.w, b1.x, b1.y, b1.z, b1.w};
                #pragma unroll
                for (int i = 0; i < 8; ++i)
                    #pragma unroll
                    for (int j = 0; j < 8; ++j)
                        acc[i][j] = fmaf(a[i], b[j], acc[i][j]);
            }
        }
        // score = |e_k|^2 - 2 * (xb . e_k); keep running min (first-min ties)
        #pragma unroll
        for (int j = 0; j < 8; ++j) {
            int k = kbase + tj * 8 + j;
            float c = ws[WS_CNORM + k];
            #pragma unroll
            for (int i = 0; i < 8; ++i) {
                float s = fmaf(-2.f, acc[i][j], c);
                if (s < minv[i]) { minv[i] = s; mini[i] = k; }
            }
        }
    }

    // ---- cross-thread argmin reduction (reuse Bs)
    __syncthreads();
    float* redv = Bs;                  // RB*64 floats
    int*   redi = (int*)(Bs + RB * 64);
    #pragma unroll
    for (int i = 0; i < 8; ++i) {
        int r = ti * 8 + i;
        redv[r * 64 + tj] = minv[i];
        redi[r * 64 + tj] = mini[i];
    }
    __syncthreads();
    if (tid < RB) {
        int r = tid;
        float bv = redv[r * 64];
        int bi = redi[r * 64];
        for (int t2 = 1; t2 < 64; ++t2) {
            float v = redv[r * 64 + t2];
            int ii = redi[r * 64 + t2];
            if (v < bv || (v == bv && ii < bi)) { bv = v; bi = ii; }
        }
        int m = mask[row0 + r];
        idxs_sh[r] = bi;
        msh[r] = (float)m;
        out[IDX_OFF + row0 + r] = m ? (float)bi : -1.0f;
        if (m) atomicAdd(&ws[WS_COUNTS + bi], 1.0f);
    }
    __syncthreads();

    // ---- epilogue: quantized output + loss partial
    float lacc = 0.f;
    #pragma unroll 4
    for (int r = 0; r < RB; ++r) {
        int idx = idxs_sh[r];
        float m = msh[r];
        float q = e[(size_t)tid * KC + idx];
        float xb = As[tid * APAD + r];
        float diff = xb - q;
        lacc = fmaf(m * diff, diff, lacc);
        out[(size_t)(row0 + r) * DIM + tid] = (m != 0.f) ? q : 0.f;
    }
    #pragma unroll
    for (int off = 32; off > 0; off >>= 1) lacc += __shfl_down(lacc, off, 64);
    if ((tid & 63) == 0) wred[tid >> 6] = lacc;
    __syncthreads();
    if (tid == 0)
        atomicAdd(&ws[WS_LOSS], wred[0] + wred[1] + wred[2] + wred[3]);
}

// ---------------------------------------------------------------- kernel 4
// Losses + perplexity
__global__ __launch_bounds__(256) void k_final(const float* __restrict__ ws,
                                               float* __restrict__ out) {
    int t = threadIdx.x;
    __shared__ float wr[4];
    float nv = ws[WS_NV];
    float acc = 0.f;
    for (int j = t; j < KC; j += 256) {
        float p = ws[WS_COUNTS + j] / nv;
        acc = fmaf(p, logf(p + 1e-10f), acc);
    }
    #pragma unroll
    for (int off = 32; off > 0; off >>= 1) acc += __shfl_down(acc, off, 64);
    if ((t & 63) == 0) wr[t >> 6] = acc;
    __syncthreads();
    if (t == 0) {
        float ent = wr[0] + wr[1] + wr[2] + wr[3];
        float loss = ws[WS_LOSS] / (nv * (float)DIM);
        out[LOSS0_OFF] = loss;
        out[LOSS1_OFF] = loss;   // forward values identical
        out[PERP_OFF] = expf(-ent);
    }
}

// ---------------------------------------------------------------- launch
extern "C" void kernel_launch(void* const* d_in, const int* in_sizes, int n_in,
                              void* d_out, int out_size, void* d_ws, size_t ws_size,
                              hipStream_t stream) {
    const float* x     = (const float*)d_in[0];
    const int*   amask = (const int*)d_in[1];
    const float* e     = (const float*)d_in[2];
    const float* gamma = (const float*)d_in[3];
    const float* beta  = (const float*)d_in[4];
    float* out = (float*)d_out;
    float* ws  = (float*)d_ws;

    // zero the accumulator region (sums, count, loss, counts histogram)
    hipMemsetAsync(d_ws, 0, 8192, stream);

    k_stats<<<512, 256, 0, stream>>>(x, amask, ws);
    k_finalize<<<5, 256, 0, stream>>>(e, gamma, ws);
    k_main<<<BN / RB, 256, 0, stream>>>(x, amask, e, beta, ws, out);
    k_final<<<1, 256, 0, stream>>>(ws, out);
}